// Round 10
// baseline (411.813 us; speedup 1.0000x reference)
//
#include <hip/hip_runtime.h>
#include <hip/hip_fp16.h>

// Problem constants (fixed by the reference file)
#define M_DIM 16384   // B*S = 4*4096
#define N_DIM 4096    // DOUT
#define K_DIM 4096    // DIN

typedef __attribute__((ext_vector_type(16))) float f32x16;
typedef __attribute__((ext_vector_type(4)))  int   i32x4;
typedef __attribute__((ext_vector_type(8)))  int   i32x8;

union frag_u { i32x8 v; i32x4 h[2]; };

// ---------------------------------------------------------------------------
// Quantize fp32 (fp16-exact values) -> fp8 RNE, emitting the 32x32x64 MFMA
// fragment-order tiled layout for 256-row blocks (UNCHANGED, verified r3-r8):
//   out = [nrow/256][K/64] tiles of 16384 B.
//   tile byte p = sb*2048 + half*1024 + l*16 + b   (sb 0..7, half 0..1,
//   l 0..63, b 0..15) holds element
//     row = tile_r*256 + sb*32 + (l&31)
//     k   = tile_k*64  + (l>>5)*32 + half*16 + b
//   Lane l's v_mfma_f32_32x32x64_f8f6f4 fragment = two contiguous 16B reads
//   at (base, base+1024) -> conflict-free LDS reads AND coalesced global
//   reads (the same layout serves both paths).
// E4M3=true -> OCP e4m3fn (weight); false -> OCP e5m2 (activations).
// ---------------------------------------------------------------------------
template<bool E4M3>
__global__ __launch_bounds__(256) void quant_tile_kernel(
    const float* __restrict__ in,   // [R, K_DIM] row-major f32
    uint4* __restrict__ out,        // tiled fp8 bytes, R*K_DIM/16 groups
    int ngrp)
{
  int t = blockIdx.x * 256 + threadIdx.x;
  if (t >= ngrp) return;
  const int g    = t & 1023;        // 16-byte group within 16 KiB tile
  const int tile = t >> 10;
  const int kt   = tile & 63;       // K/64 = 64 K-tiles
  const int bt   = tile >> 6;       // 256-row block
  const int sb   = g >> 7;          // 32-row sub-block (0..7)
  const int half = (g >> 6) & 1;
  const int l    = g & 63;
  const int row  = bt * 256 + sb * 32 + (l & 31);
  const int k    = kt * 64 + (l >> 5) * 32 + half * 16;

  const float4* p = reinterpret_cast<const float4*>(in + (size_t)row * K_DIM + k);
  float4 v0 = p[0], v1 = p[1], v2 = p[2], v3 = p[3];
  int w0 = 0, w1 = 0, w2 = 0, w3 = 0;
  if (E4M3) {
    w0 = __builtin_amdgcn_cvt_pk_fp8_f32(v0.x, v0.y, w0, false);
    w0 = __builtin_amdgcn_cvt_pk_fp8_f32(v0.z, v0.w, w0, true);
    w1 = __builtin_amdgcn_cvt_pk_fp8_f32(v1.x, v1.y, w1, false);
    w1 = __builtin_amdgcn_cvt_pk_fp8_f32(v1.z, v1.w, w1, true);
    w2 = __builtin_amdgcn_cvt_pk_fp8_f32(v2.x, v2.y, w2, false);
    w2 = __builtin_amdgcn_cvt_pk_fp8_f32(v2.z, v2.w, w2, true);
    w3 = __builtin_amdgcn_cvt_pk_fp8_f32(v3.x, v3.y, w3, false);
    w3 = __builtin_amdgcn_cvt_pk_fp8_f32(v3.z, v3.w, w3, true);
  } else {
    w0 = __builtin_amdgcn_cvt_pk_bf8_f32(v0.x, v0.y, w0, false);
    w0 = __builtin_amdgcn_cvt_pk_bf8_f32(v0.z, v0.w, w0, true);
    w1 = __builtin_amdgcn_cvt_pk_bf8_f32(v1.x, v1.y, w1, false);
    w1 = __builtin_amdgcn_cvt_pk_bf8_f32(v1.z, v1.w, w1, true);
    w2 = __builtin_amdgcn_cvt_pk_bf8_f32(v2.x, v2.y, w2, false);
    w2 = __builtin_amdgcn_cvt_pk_bf8_f32(v2.z, v2.w, w2, true);
    w3 = __builtin_amdgcn_cvt_pk_bf8_f32(v3.x, v3.y, w3, false);
    w3 = __builtin_amdgcn_cvt_pk_bf8_f32(v3.z, v3.w, w3, true);
  }
  out[t] = make_uint4((unsigned)w0, (unsigned)w1, (unsigned)w2, (unsigned)w3);
}

// ---------------------------------------------------------------------------
// MX-fp8 GEMM — B-in-registers, 1-barrier-per-tile: 256x256 block tile,
// BK=64, 8 waves (2M x 4N), per-wave 128x64 = acc[4][2] f32x16, 2 waves/SIMD.
//   A: global_load_lds -> 3 x 16 KiB rotating LDS bufs; plain ds_read_b128
//      frags (compiler inserts per-MFMA counted lgkm -> natural interleave).
//   B: plain i32x4 global loads direct to regs (L2-resident panel),
//      double-buffered bE/bO, issued one tile ahead (compiler inserts the
//      counted vmcnt before use).
// Cross-wave ordering (the one thing the compiler can't see): each tile
// issues exactly 6 VMEM ops (4 B + 2 A-stage), so `vmcnt(6)` at tile end
// proves all ops issued before the PREVIOUS tile retired => A(t+1) landed;
// the s_barrier makes it block-wide. ds_reads are drained pre-barrier
// because their MFMA uses (pinned by sched_barrier) force the lgkm wait.
// ---------------------------------------------------------------------------
__global__ __launch_bounds__(512, 2) void gemm_fp8_kernel(
    const unsigned char* __restrict__ Aq,   // tiled [64][64][16384] e5m2
    const unsigned char* __restrict__ Wq,   // tiled [16][64][16384] e4m3
    const float* __restrict__ bias,         // [N] fp16-exact values in f32
    float* __restrict__ C)                  // [M,N] f32 (fp16-rounded values)
{
  __shared__ __align__(16) unsigned char lds[49152];  // 3 x 16 KiB A bufs

  const int tid  = threadIdx.x;
  const int lane = tid & 63;
  const int wave = tid >> 6;                // 0..7
  const int wr   = wave >> 2;               // 0..1 -> 128 rows
  const int wc   = wave & 3;                // 0..3 -> 64 cols

  // T1: XCD swizzle, r4 mapping (measured best FETCH).
  const int bid = blockIdx.x;
  const int swz = (bid & 7) * 128 + (bid >> 3);
  const int bmi = swz >> 4;                 // 0..63
  const int bni = swz & 15;                 // 0..15

  const unsigned char* tA = Aq + (size_t)bmi * (64 * 16384);
  const unsigned char* tB = Wq + (size_t)bni * (64 * 16384);

  const size_t t16 = (size_t)tid * 16;      // per-lane A-stage offset
  const int    w1k = wave * 1024;           // wave-uniform LDS sub-offset
  // Per-lane B fragment base: frags at +0,+2048; halves at +0,+1024.
  const unsigned char* gbp = tB + wc * 4096 + lane * 16;

  // Stage one 8 KiB A piece: 512 thr x 16 B, linear.
#define STAGE(gb, lo_)                                                      \
  __builtin_amdgcn_global_load_lds(                                        \
      (const __attribute__((address_space(1))) void*)((gb) + t16),          \
      (__attribute__((address_space(3))) void*)(lds + (lo_) + w1k), 16, 0, 0)

  // A fragment: two contiguous ds_read_b128 (plain C, compiler-managed lgkm).
#define RD8(dst, off)                                                       \
  { const unsigned char* _p = lds + (off) + lane * 16;                      \
    (dst).h[0] = *reinterpret_cast<const i32x4*>(_p);                       \
    (dst).h[1] = *reinterpret_cast<const i32x4*>(_p + 1024); }

  // B fragment: two plain 16B global loads (compiler-managed vmcnt).
#define LDB(dst, p)                                                         \
  { (dst).h[0] = *reinterpret_cast<const i32x4*>(p);                        \
    (dst).h[1] = *reinterpret_cast<const i32x4*>((p) + 1024); }

#define MFMA(d, a, b)                                                       \
  d = __builtin_amdgcn_mfma_scale_f32_32x32x64_f8f6f4(                      \
      a, b, d, 1 /*A=e5m2*/, 0 /*B=e4m3*/, 0, 0x7F7F7F7F, 0, 0x7F7F7F7F)

#define SBAR __builtin_amdgcn_sched_barrier(0)
#define BAR  { SBAR; __builtin_amdgcn_s_barrier(); SBAR; }
#define VMW6 { asm volatile("s_waitcnt vmcnt(6)" ::: "memory"); SBAR; }
#define P1   __builtin_amdgcn_s_setprio(1)
#define P0   __builtin_amdgcn_s_setprio(0)

  const int aoff = wr * 8192;               // A frag base within a 16K buf

  f32x16 acc[4][2] = {};
  frag_u a0, a1, a2, a3, bE0, bE1, bO0, bO1;

  // ---- Prologue. Issue order (pinned): A(0)x2 | B(0)x4, A(1)x2.
  STAGE(tA, 0); STAGE(tA + 8192, 8192);                 // A(0) -> buf0
  SBAR;
  LDB(bE0, gbp); LDB(bE1, gbp + 2048);                  // B(0) -> regs
  STAGE(tA + 16384, 16384); STAGE(tA + 24576, 24576);   // A(1) -> buf1
  SBAR;
  VMW6;                                     // 8 outstanding -> 6: A(0) landed
  BAR;

  int cA = 0, cB = 16384, cC = 32768;       // bufs of tiles t, t+1, t+2

  for (int it = 0; it < 32; ++it) {
    const int t = it << 1;
    // ===== EVEN tile t: A frags from cA, B = bE; load B(t+1)->bO;
    //       stage A(t+2) -> cC (free since the barrier ending tile t-1).
    {
      const size_t tpB = (size_t)((t + 1) & 63) * 16384;
      const size_t tpA = (size_t)((t + 2) & 63) * 16384;
      LDB(bO0, gbp + tpB); LDB(bO1, gbp + tpB + 2048);
      STAGE(tA + tpA, cC); STAGE(tA + tpA + 8192, cC + 8192);
      SBAR;
      RD8(a0, cA + aoff);        RD8(a1, cA + aoff + 2048);
      RD8(a2, cA + aoff + 4096); RD8(a3, cA + aoff + 6144);
      P1;
      MFMA(acc[0][0], a0.v, bE0.v); MFMA(acc[0][1], a0.v, bE1.v);
      MFMA(acc[1][0], a1.v, bE0.v); MFMA(acc[1][1], a1.v, bE1.v);
      MFMA(acc[2][0], a2.v, bE0.v); MFMA(acc[2][1], a2.v, bE1.v);
      MFMA(acc[3][0], a3.v, bE0.v); MFMA(acc[3][1], a3.v, bE1.v);
      P0;
      VMW6;                                 // all pre-tile-t ops retired:
      BAR;                                  // A(t+1) in cB, block-wide
    }
    // ===== ODD tile t+1: A frags from cB, B = bO; load B(t+2)->bE;
    //       stage A(t+3) -> cA (free since the barrier above).
    {
      const size_t tpB = (size_t)((t + 2) & 63) * 16384;
      const size_t tpA = (size_t)((t + 3) & 63) * 16384;
      LDB(bE0, gbp + tpB); LDB(bE1, gbp + tpB + 2048);
      STAGE(tA + tpA, cA); STAGE(tA + tpA + 8192, cA + 8192);
      SBAR;
      RD8(a0, cB + aoff);        RD8(a1, cB + aoff + 2048);
      RD8(a2, cB + aoff + 4096); RD8(a3, cB + aoff + 6144);
      P1;
      MFMA(acc[0][0], a0.v, bO0.v); MFMA(acc[0][1], a0.v, bO1.v);
      MFMA(acc[1][0], a1.v, bO0.v); MFMA(acc[1][1], a1.v, bO1.v);
      MFMA(acc[2][0], a2.v, bO0.v); MFMA(acc[2][1], a2.v, bO1.v);
      MFMA(acc[3][0], a3.v, bO0.v); MFMA(acc[3][1], a3.v, bO1.v);
      P0;
      VMW6;                                 // A(t+2) landed (in cC)
      BAR;
    }
    // Rotate: tiles (t+2, t+3, t+4) -> (cC, cA, cB).
    const int nA = cC, nB = cA, nC = cB;
    cA = nA; cB = nB; cC = nC;
  }
#undef STAGE
#undef RD8
#undef LDB
#undef MFMA
#undef SBAR
#undef BAR
#undef VMW6
#undef P1
#undef P0

  // Epilogue: +bias, round through fp16 (matches reference), store f32.
  // 32x32 C/D layout (verified r3-r8): col = lane&31,
  // row = (r&3) + 8*(r>>2) + 4*(lane>>5).
  #pragma unroll
  for (int n = 0; n < 2; ++n) {
    const int col = bni * 256 + wc * 64 + n * 32 + (lane & 31);
    const float bv = bias[col];
    #pragma unroll
    for (int m = 0; m < 4; ++m) {
      const int rbase = bmi * 256 + wr * 128 + m * 32 + ((lane >> 5) << 2);
      #pragma unroll
      for (int r = 0; r < 16; ++r) {
        const int row = rbase + (r & 3) + 8 * (r >> 2);
        C[(size_t)row * N_DIM + col] =
            __half2float(__float2half_rn(acc[m][n][r] + bv));
      }
    }
  }
}

// ---------------------------------------------------------------------------
extern "C" void kernel_launch(void* const* d_in, const int* in_sizes, int n_in,
                              void* d_out, int out_size, void* d_ws, size_t ws_size,
                              hipStream_t stream) {
  const float* x  = (const float*)d_in[0];   // [B,S,DIN] fp16-exact values in f32
  const float* w  = (const float*)d_in[1];   // [DOUT,DIN]
  const float* bs = (const float*)d_in[2];   // [DOUT]
  float* out = (float*)d_out;

  // Workspace: xq = 64 MiB e5m2 (tiled), wq = 16 MiB e4m3 (tiled)
  unsigned char* xq = (unsigned char*)d_ws;
  unsigned char* wq = (unsigned char*)d_ws + (size_t)M_DIM * K_DIM;

  const int ngx = (M_DIM * K_DIM) / 16;   // 4,194,304 groups
  const int ngw = (N_DIM * K_DIM) / 16;   // 1,048,576 groups
  quant_tile_kernel<false><<<ngx / 256, 256, 0, stream>>>(x, (uint4*)xq, ngx);
  quant_tile_kernel<true ><<<ngw / 256, 256, 0, stream>>>(w, (uint4*)wq, ngw);

  gemm_fp8_kernel<<<1024, 512, 0, stream>>>(xq, wq, bs, out);
}

// Round 11
// 352.936 us; speedup vs baseline: 1.1668x; 1.1668x over previous
//
#include <hip/hip_runtime.h>
#include <hip/hip_fp16.h>

// Problem constants (fixed by the reference file)
#define M_DIM 16384   // B*S = 4*4096
#define N_DIM 4096    // DOUT
#define K_DIM 4096    // DIN

typedef __attribute__((ext_vector_type(16))) float f32x16;
typedef __attribute__((ext_vector_type(4)))  int   i32x4;
typedef __attribute__((ext_vector_type(8)))  int   i32x8;

union frag_u { i32x8 v; i32x4 h[2]; };

// ---------------------------------------------------------------------------
// Quantize fp32 (fp16-exact values) -> fp8 RNE, emitting the 32x32x64 MFMA
// fragment-order tiled layout for 256-row blocks (UNCHANGED, verified r3-r10):
//   out = [nrow/256][K/64] tiles of 16384 B.
//   tile byte p = sb*2048 + half*1024 + l*16 + b   (sb 0..7, half 0..1,
//   l 0..63, b 0..15) holds element
//     row = tile_r*256 + sb*32 + (l&31)
//     k   = tile_k*64  + (l>>5)*32 + half*16 + b
//   Lane l's v_mfma_f32_32x32x64_f8f6f4 fragment = two contiguous 16B reads
//   at (base, base+1024) -> conflict-free LDS reads; staging is linear.
// E4M3=true -> OCP e4m3fn (weight); false -> OCP e5m2 (activations).
// ---------------------------------------------------------------------------
template<bool E4M3>
__global__ __launch_bounds__(256) void quant_tile_kernel(
    const float* __restrict__ in,   // [R, K_DIM] row-major f32
    uint4* __restrict__ out,        // tiled fp8 bytes, R*K_DIM/16 groups
    int ngrp)
{
  int t = blockIdx.x * 256 + threadIdx.x;
  if (t >= ngrp) return;
  const int g    = t & 1023;        // 16-byte group within 16 KiB tile
  const int tile = t >> 10;
  const int kt   = tile & 63;       // K/64 = 64 K-tiles
  const int bt   = tile >> 6;       // 256-row block
  const int sb   = g >> 7;          // 32-row sub-block (0..7)
  const int half = (g >> 6) & 1;
  const int l    = g & 63;
  const int row  = bt * 256 + sb * 32 + (l & 31);
  const int k    = kt * 64 + (l >> 5) * 32 + half * 16;

  const float4* p = reinterpret_cast<const float4*>(in + (size_t)row * K_DIM + k);
  float4 v0 = p[0], v1 = p[1], v2 = p[2], v3 = p[3];
  int w0 = 0, w1 = 0, w2 = 0, w3 = 0;
  if (E4M3) {
    w0 = __builtin_amdgcn_cvt_pk_fp8_f32(v0.x, v0.y, w0, false);
    w0 = __builtin_amdgcn_cvt_pk_fp8_f32(v0.z, v0.w, w0, true);
    w1 = __builtin_amdgcn_cvt_pk_fp8_f32(v1.x, v1.y, w1, false);
    w1 = __builtin_amdgcn_cvt_pk_fp8_f32(v1.z, v1.w, w1, true);
    w2 = __builtin_amdgcn_cvt_pk_fp8_f32(v2.x, v2.y, w2, false);
    w2 = __builtin_amdgcn_cvt_pk_fp8_f32(v2.z, v2.w, w2, true);
    w3 = __builtin_amdgcn_cvt_pk_fp8_f32(v3.x, v3.y, w3, false);
    w3 = __builtin_amdgcn_cvt_pk_fp8_f32(v3.z, v3.w, w3, true);
  } else {
    w0 = __builtin_amdgcn_cvt_pk_bf8_f32(v0.x, v0.y, w0, false);
    w0 = __builtin_amdgcn_cvt_pk_bf8_f32(v0.z, v0.w, w0, true);
    w1 = __builtin_amdgcn_cvt_pk_bf8_f32(v1.x, v1.y, w1, false);
    w1 = __builtin_amdgcn_cvt_pk_bf8_f32(v1.z, v1.w, w1, true);
    w2 = __builtin_amdgcn_cvt_pk_bf8_f32(v2.x, v2.y, w2, false);
    w2 = __builtin_amdgcn_cvt_pk_bf8_f32(v2.z, v2.w, w2, true);
    w3 = __builtin_amdgcn_cvt_pk_bf8_f32(v3.x, v3.y, w3, false);
    w3 = __builtin_amdgcn_cvt_pk_bf8_f32(v3.z, v3.w, w3, true);
  }
  out[t] = make_uint4((unsigned)w0, (unsigned)w1, (unsigned)w2, (unsigned)w3);
}

// ---------------------------------------------------------------------------
// MX-fp8 GEMM — enforced-overlap pipeline: 256x256 block tile, BK=64,
// 8 waves (2M x 4N), per-wave 128x64 = acc[4][2] f32x16, 2 waves/SIMD.
// LDS: 4 buffers x {A 16K | B 16K} = 128 KiB; tile T lives in buf[T&3].
// Per tile t: {SBAR; 12 plain ds_reads for tile t+1; SBAR; setprio+8 MFMA
// on tile-t frags (compiler-counted lgkm gates them); SBAR; stage tile t+3;
// vmcnt(4) [proves t+2 staged]; BAR}. One barrier per tile; reads pinned
// BEFORE the MFMA cluster so the LDS pipe works concurrently with MFMA.
// Stage 3 ahead / read 1 ahead / confirm 2 ahead — ledger exact incl. tail.
// ---------------------------------------------------------------------------
__global__ __launch_bounds__(512, 2) void gemm_fp8_kernel(
    const unsigned char* __restrict__ Aq,   // tiled [64][64][16384] e5m2
    const unsigned char* __restrict__ Wq,   // tiled [16][64][16384] e4m3
    const float* __restrict__ bias,         // [N] fp16-exact values in f32
    float* __restrict__ C)                  // [M,N] f32 (fp16-rounded values)
{
  __shared__ __align__(16) unsigned char lds[131072];  // 4 x {A 16K, B 16K}

  const int tid  = threadIdx.x;
  const int lane = tid & 63;
  const int wave = tid >> 6;                // 0..7
  const int wr   = wave >> 2;               // 0..1 -> 128 rows
  const int wc   = wave & 3;                // 0..3 -> 64 cols

  // T1: XCD swizzle, r4 mapping (measured best FETCH).
  const int bid = blockIdx.x;
  const int swz = (bid & 7) * 128 + (bid >> 3);
  const int bmi = swz >> 4;                 // 0..63
  const int bni = swz & 15;                 // 0..15

  const unsigned char* tA = Aq + (size_t)bmi * (64 * 16384);
  const unsigned char* tB = Wq + (size_t)bni * (64 * 16384);

  const size_t t16 = (size_t)tid * 16;      // per-lane staging offset
  const int    w1k = wave * 1024;           // wave-uniform LDS sub-offset

  // Stage one 8 KiB piece: 512 thr x 16 B, linear.
#define STAGE(gb, lo_)                                                      \
  __builtin_amdgcn_global_load_lds(                                        \
      (const __attribute__((address_space(1))) void*)((gb) + t16),          \
      (__attribute__((address_space(3))) void*)(lds + (lo_) + w1k), 16, 0, 0)

  // Stage one K-tile (A 16 KiB + B 16 KiB): 4 insts/wave.
#define STAGE_TILE(tp, base)                                                \
  STAGE(tA + (tp), (base));          STAGE(tA + (tp) + 8192, (base) + 8192); \
  STAGE(tB + (tp), (base) + 16384);  STAGE(tB + (tp) + 8192, (base) + 24576)

  // One fragment = two contiguous ds_read_b128 (plain C: compiler-visible,
  // compiler inserts exact counted lgkm before the consuming MFMA).
#define RD8(dst, off)                                                       \
  { const unsigned char* _p = lds + (off) + lane * 16;                      \
    (dst).h[0] = *reinterpret_cast<const i32x4*>(_p);                       \
    (dst).h[1] = *reinterpret_cast<const i32x4*>(_p + 1024); }

#define MFMA(d, a, b)                                                       \
  d = __builtin_amdgcn_mfma_scale_f32_32x32x64_f8f6f4(                      \
      a, b, d, 1 /*A=e5m2*/, 0 /*B=e4m3*/, 0, 0x7F7F7F7F, 0, 0x7F7F7F7F)

#define SBAR __builtin_amdgcn_sched_barrier(0)
#define P1   __builtin_amdgcn_s_setprio(1)
#define P0   __builtin_amdgcn_s_setprio(0)

  const int aoff = wr * 8192;               // A frag base within a buf
  const int boff = 16384 + wc * 4096;       // B frag base within a buf

  f32x16 acc[4][2] = {};
  frag_u Ea0, Ea1, Ea2, Ea3, Eb0, Eb1;      // frag set E
  frag_u Oa0, Oa1, Oa2, Oa3, Ob0, Ob1;      // frag set O

  // rdset <- 12 reads of one tile's frags from LDS buffer `buf`.
#define RDTILE(s, buf)                                                      \
  RD8(s##a0, (buf) + aoff);        RD8(s##a1, (buf) + aoff + 2048);         \
  RD8(s##a2, (buf) + aoff + 4096); RD8(s##a3, (buf) + aoff + 6144);         \
  RD8(s##b0, (buf) + boff);        RD8(s##b1, (buf) + boff + 2048)

  // One tile step: read next tile's frags (pinned first), MFMA current,
  // stage tile+3, confirm tile+2, block barrier.
#define TILE_STEP(rdset, mfset, rdbuf, stbuf, tp3)                          \
  SBAR;                                                                     \
  RDTILE(rdset, rdbuf);                                                     \
  SBAR;                                                                     \
  P1;                                                                       \
  MFMA(acc[0][0], mfset##a0.v, mfset##b0.v);                                \
  MFMA(acc[0][1], mfset##a0.v, mfset##b1.v);                                \
  MFMA(acc[1][0], mfset##a1.v, mfset##b0.v);                                \
  MFMA(acc[1][1], mfset##a1.v, mfset##b1.v);                                \
  MFMA(acc[2][0], mfset##a2.v, mfset##b0.v);                                \
  MFMA(acc[2][1], mfset##a2.v, mfset##b1.v);                                \
  MFMA(acc[3][0], mfset##a3.v, mfset##b0.v);                                \
  MFMA(acc[3][1], mfset##a3.v, mfset##b1.v);                                \
  P0;                                                                       \
  SBAR;                                                                     \
  STAGE_TILE(tp3, stbuf);                                                   \
  SBAR;                                                                     \
  asm volatile("s_waitcnt vmcnt(4)" ::: "memory");                          \
  SBAR;                                                                     \
  __builtin_amdgcn_s_barrier()

  // ---- Prologue: stage tiles 0,1,2 -> bufs 0,1,2 (12 insts).
  STAGE_TILE(0, 0);
  STAGE_TILE(16384, 32768);
  STAGE_TILE(32768, 65536);
  SBAR;
  asm volatile("s_waitcnt vmcnt(4)" ::: "memory");   // tiles 0,1 landed
  SBAR;
  __builtin_amdgcn_s_barrier();
  SBAR;
  RDTILE(E, 0);                                      // frags of tile 0
  SBAR;

  for (int it = 0; it < 16; ++it) {
    const int t = it << 2;
    const size_t tp3 = (size_t)((t + 3) & 63) * 16384;
    const size_t tp4 = (size_t)((t + 4) & 63) * 16384;
    const size_t tp5 = (size_t)((t + 5) & 63) * 16384;
    const size_t tp6 = (size_t)((t + 6) & 63) * 16384;
    // tile t   (buf0): read t+1 from buf1, stage t+3 -> buf3
    TILE_STEP(O, E, 32768, 98304, tp3);
    // tile t+1 (buf1): read t+2 from buf2, stage t+4 -> buf0
    TILE_STEP(E, O, 65536, 0, tp4);
    // tile t+2 (buf2): read t+3 from buf3, stage t+5 -> buf1
    TILE_STEP(O, E, 98304, 32768, tp5);
    // tile t+3 (buf3): read t+4 from buf0, stage t+6 -> buf2
    TILE_STEP(E, O, 0, 65536, tp6);
  }
#undef STAGE
#undef STAGE_TILE
#undef RD8
#undef RDTILE
#undef MFMA
#undef TILE_STEP
#undef SBAR
#undef P1
#undef P0

  // Epilogue: +bias, round through fp16 (matches reference), store f32.
  // 32x32 C/D layout (verified r3-r10): col = lane&31,
  // row = (r&3) + 8*(r>>2) + 4*(lane>>5).
  #pragma unroll
  for (int n = 0; n < 2; ++n) {
    const int col = bni * 256 + wc * 64 + n * 32 + (lane & 31);
    const float bv = bias[col];
    #pragma unroll
    for (int m = 0; m < 4; ++m) {
      const int rbase = bmi * 256 + wr * 128 + m * 32 + ((lane >> 5) << 2);
      #pragma unroll
      for (int r = 0; r < 16; ++r) {
        const int row = rbase + (r & 3) + 8 * (r >> 2);
        C[(size_t)row * N_DIM + col] =
            __half2float(__float2half_rn(acc[m][n][r] + bv));
      }
    }
  }
}

// ---------------------------------------------------------------------------
extern "C" void kernel_launch(void* const* d_in, const int* in_sizes, int n_in,
                              void* d_out, int out_size, void* d_ws, size_t ws_size,
                              hipStream_t stream) {
  const float* x  = (const float*)d_in[0];   // [B,S,DIN] fp16-exact values in f32
  const float* w  = (const float*)d_in[1];   // [DOUT,DIN]
  const float* bs = (const float*)d_in[2];   // [DOUT]
  float* out = (float*)d_out;

  // Workspace: xq = 64 MiB e5m2 (tiled), wq = 16 MiB e4m3 (tiled)
  unsigned char* xq = (unsigned char*)d_ws;
  unsigned char* wq = (unsigned char*)d_ws + (size_t)M_DIM * K_DIM;

  const int ngx = (M_DIM * K_DIM) / 16;   // 4,194,304 groups
  const int ngw = (N_DIM * K_DIM) / 16;   // 1,048,576 groups
  quant_tile_kernel<false><<<ngx / 256, 256, 0, stream>>>(x, (uint4*)xq, ngx);
  quant_tile_kernel<true ><<<ngw / 256, 256, 0, stream>>>(w, (uint4*)wq, ngw);

  gemm_fp8_kernel<<<1024, 512, 0, stream>>>(xq, wq, bs, out);
}

// Round 12
// 347.746 us; speedup vs baseline: 1.1842x; 1.0149x over previous
//
#include <hip/hip_runtime.h>
#include <hip/hip_fp16.h>

// Problem constants (fixed by the reference file)
#define M_DIM 16384   // B*S = 4*4096
#define N_DIM 4096    // DOUT
#define K_DIM 4096    // DIN

typedef __attribute__((ext_vector_type(16))) float f32x16;
typedef __attribute__((ext_vector_type(4)))  int   i32x4;
typedef __attribute__((ext_vector_type(8)))  int   i32x8;

union frag_u { i32x8 v; i32x4 h[2]; };

// ---------------------------------------------------------------------------
// Fused quantizer (x -> e5m2, w -> e4m3fn), fp32-in (fp16-exact), RNE via
// hardware cvt_pk. Emits the 32x32x64 MFMA fragment-order tiled layout
// (UNCHANGED, verified r3-r11): out = [nrow/256][K/64] tiles of 16384 B;
// tile byte p = sb*2048 + half*1024 + l*16 + b  ->  row = 256*bt + sb*32 +
// (l&31), k = 64*kt + (l>>5)*32 + half*16 + b.
// Single launch covers both tensors (blocks [0,16384) = x, rest = w).
// ---------------------------------------------------------------------------
__global__ __launch_bounds__(256) void quant_fused_kernel(
    const float* __restrict__ x, const float* __restrict__ w,
    uint4* __restrict__ xq, uint4* __restrict__ wq)
{
  const int b = blockIdx.x;
  const float* in;
  uint4* out;
  int t;
  bool e4m3;
  if (b < 16384) { in = x; out = xq; t = b * 256 + threadIdx.x; e4m3 = false; }
  else { in = w; out = wq; t = (b - 16384) * 256 + threadIdx.x; e4m3 = true; }

  const int g    = t & 1023;        // 16-byte group within 16 KiB tile
  const int tile = t >> 10;
  const int kt   = tile & 63;       // K/64 = 64 K-tiles
  const int bt   = tile >> 6;       // 256-row block
  const int sb   = g >> 7;          // 32-row sub-block (0..7)
  const int half = (g >> 6) & 1;
  const int l    = g & 63;
  const int row  = bt * 256 + sb * 32 + (l & 31);
  const int k    = kt * 64 + (l >> 5) * 32 + half * 16;

  const float4* p = reinterpret_cast<const float4*>(in + (size_t)row * K_DIM + k);
  float4 v0 = p[0], v1 = p[1], v2 = p[2], v3 = p[3];
  int w0 = 0, w1 = 0, w2 = 0, w3 = 0;
  if (e4m3) {
    w0 = __builtin_amdgcn_cvt_pk_fp8_f32(v0.x, v0.y, w0, false);
    w0 = __builtin_amdgcn_cvt_pk_fp8_f32(v0.z, v0.w, w0, true);
    w1 = __builtin_amdgcn_cvt_pk_fp8_f32(v1.x, v1.y, w1, false);
    w1 = __builtin_amdgcn_cvt_pk_fp8_f32(v1.z, v1.w, w1, true);
    w2 = __builtin_amdgcn_cvt_pk_fp8_f32(v2.x, v2.y, w2, false);
    w2 = __builtin_amdgcn_cvt_pk_fp8_f32(v2.z, v2.w, w2, true);
    w3 = __builtin_amdgcn_cvt_pk_fp8_f32(v3.x, v3.y, w3, false);
    w3 = __builtin_amdgcn_cvt_pk_fp8_f32(v3.z, v3.w, w3, true);
  } else {
    w0 = __builtin_amdgcn_cvt_pk_bf8_f32(v0.x, v0.y, w0, false);
    w0 = __builtin_amdgcn_cvt_pk_bf8_f32(v0.z, v0.w, w0, true);
    w1 = __builtin_amdgcn_cvt_pk_bf8_f32(v1.x, v1.y, w1, false);
    w1 = __builtin_amdgcn_cvt_pk_bf8_f32(v1.z, v1.w, w1, true);
    w2 = __builtin_amdgcn_cvt_pk_bf8_f32(v2.x, v2.y, w2, false);
    w2 = __builtin_amdgcn_cvt_pk_bf8_f32(v2.z, v2.w, w2, true);
    w3 = __builtin_amdgcn_cvt_pk_bf8_f32(v3.x, v3.y, w3, false);
    w3 = __builtin_amdgcn_cvt_pk_bf8_f32(v3.z, v3.w, w3, true);
  }
  out[t] = make_uint4((unsigned)w0, (unsigned)w1, (unsigned)w2, (unsigned)w3);
}

// ---------------------------------------------------------------------------
// MX-fp8 GEMM — r11 pipeline + WAVE-GROUP PHASE STAGGER: 256x256 block tile,
// BK=64, 8 waves (2M x 4N), per-wave 128x64 = acc[4][2] f32x16, 2 waves/SIMD.
// LDS: 4 buffers x {A 16K | B 16K} = 128 KiB; tile T lives in buf[T&3].
// Stagger: wr=0 waves (one per SIMD) run {reads; MFMA}; wr=1 waves run
// {MFMA; reads} — so at any instant each SIMD has one wave feeding the
// matrix pipe and one issuing LDS reads. Barrier counts identical across the
// branch; dataflow/ledger identical to r11 (stage 3 ahead / read 1 ahead /
// confirm 2 ahead; vmcnt(4) once per tile, never drained to 0).
// ---------------------------------------------------------------------------
__global__ __launch_bounds__(512, 2) void gemm_fp8_kernel(
    const unsigned char* __restrict__ Aq,   // tiled [64][64][16384] e5m2
    const unsigned char* __restrict__ Wq,   // tiled [16][64][16384] e4m3
    const float* __restrict__ bias,         // [N] fp16-exact values in f32
    float* __restrict__ C)                  // [M,N] f32 (fp16-rounded values)
{
  __shared__ __align__(16) unsigned char lds[131072];  // 4 x {A 16K, B 16K}

  const int tid  = threadIdx.x;
  const int lane = tid & 63;
  const int wave = tid >> 6;                // 0..7
  const int wr   = wave >> 2;               // 0..1 -> 128 rows; ALSO the
                                            // stagger group (waves 0-3 sit on
                                            // SIMD 0-3, waves 4-7 pair them)
  const int wc   = wave & 3;                // 0..3 -> 64 cols

  // T1: XCD swizzle, r4 mapping (measured best FETCH).
  const int bid = blockIdx.x;
  const int swz = (bid & 7) * 128 + (bid >> 3);
  const int bmi = swz >> 4;                 // 0..63
  const int bni = swz & 15;                 // 0..15

  const unsigned char* tA = Aq + (size_t)bmi * (64 * 16384);
  const unsigned char* tB = Wq + (size_t)bni * (64 * 16384);

  const size_t t16 = (size_t)tid * 16;      // per-lane staging offset
  const int    w1k = wave * 1024;           // wave-uniform LDS sub-offset

#define STAGE(gb, lo_)                                                      \
  __builtin_amdgcn_global_load_lds(                                        \
      (const __attribute__((address_space(1))) void*)((gb) + t16),          \
      (__attribute__((address_space(3))) void*)(lds + (lo_) + w1k), 16, 0, 0)

#define STAGE_TILE(tp, base)                                                \
  STAGE(tA + (tp), (base));          STAGE(tA + (tp) + 8192, (base) + 8192); \
  STAGE(tB + (tp), (base) + 16384);  STAGE(tB + (tp) + 8192, (base) + 24576)

  // One fragment = two contiguous ds_read_b128 (plain C, compiler-counted lgkm).
#define RD8(dst, off)                                                       \
  { const unsigned char* _p = lds + (off) + lane * 16;                      \
    (dst).h[0] = *reinterpret_cast<const i32x4*>(_p);                       \
    (dst).h[1] = *reinterpret_cast<const i32x4*>(_p + 1024); }

#define MFMA(d, a, b)                                                       \
  d = __builtin_amdgcn_mfma_scale_f32_32x32x64_f8f6f4(                      \
      a, b, d, 1 /*A=e5m2*/, 0 /*B=e4m3*/, 0, 0x7F7F7F7F, 0, 0x7F7F7F7F)

#define SBAR __builtin_amdgcn_sched_barrier(0)
#define P1   __builtin_amdgcn_s_setprio(1)
#define P0   __builtin_amdgcn_s_setprio(0)

  const int aoff = wr * 8192;               // A frag base within a buf
  const int boff = 16384 + wc * 4096;       // B frag base within a buf

  f32x16 acc[4][2] = {};
  frag_u Ea0, Ea1, Ea2, Ea3, Eb0, Eb1;      // frag set E
  frag_u Oa0, Oa1, Oa2, Oa3, Ob0, Ob1;      // frag set O

#define RDTILE(s, buf)                                                      \
  RD8(s##a0, (buf) + aoff);        RD8(s##a1, (buf) + aoff + 2048);         \
  RD8(s##a2, (buf) + aoff + 4096); RD8(s##a3, (buf) + aoff + 6144);         \
  RD8(s##b0, (buf) + boff);        RD8(s##b1, (buf) + boff + 2048)

#define MFMAC(s)                                                            \
  P1;                                                                       \
  MFMA(acc[0][0], s##a0.v, s##b0.v);  MFMA(acc[0][1], s##a0.v, s##b1.v);    \
  MFMA(acc[1][0], s##a1.v, s##b0.v);  MFMA(acc[1][1], s##a1.v, s##b1.v);    \
  MFMA(acc[2][0], s##a2.v, s##b0.v);  MFMA(acc[2][1], s##a2.v, s##b1.v);    \
  MFMA(acc[3][0], s##a3.v, s##b0.v);  MFMA(acc[3][1], s##a3.v, s##b1.v);    \
  P0

#define TAIL(stbuf, tp)                                                     \
  SBAR;                                                                     \
  STAGE_TILE(tp, stbuf);                                                    \
  SBAR;                                                                     \
  asm volatile("s_waitcnt vmcnt(4)" ::: "memory");                          \
  SBAR;                                                                     \
  __builtin_amdgcn_s_barrier()

  // Reads-first (group wr=0) and MFMA-first (group wr=1) tile steps.
#define TILE_RF(rdset, mfset, rdbuf, stbuf, tp)                             \
  SBAR; RDTILE(rdset, rdbuf); SBAR; MFMAC(mfset); TAIL(stbuf, tp)
#define TILE_FR(rdset, mfset, rdbuf, stbuf, tp)                             \
  SBAR; MFMAC(mfset); SBAR; RDTILE(rdset, rdbuf); TAIL(stbuf, tp)

  // ---- Prologue: stage tiles 0,1,2 -> bufs 0,1,2; read tile-0 frags.
  STAGE_TILE(0, 0);
  STAGE_TILE(16384, 32768);
  STAGE_TILE(32768, 65536);
  SBAR;
  asm volatile("s_waitcnt vmcnt(4)" ::: "memory");   // tiles 0,1 landed
  SBAR;
  __builtin_amdgcn_s_barrier();
  SBAR;
  RDTILE(E, 0);                                      // frags of tile 0
  SBAR;

  // Two whole-loop variants; barrier counts identical across the branch.
  if (wr == 0) {
    for (int it = 0; it < 16; ++it) {
      const int t = it << 2;
      const size_t tp3 = (size_t)((t + 3) & 63) * 16384;
      const size_t tp4 = (size_t)((t + 4) & 63) * 16384;
      const size_t tp5 = (size_t)((t + 5) & 63) * 16384;
      const size_t tp6 = (size_t)((t + 6) & 63) * 16384;
      TILE_RF(O, E, 32768, 98304, tp3);   // tile t   (buf0): rd t+1, st t+3
      TILE_RF(E, O, 65536, 0,     tp4);   // tile t+1 (buf1): rd t+2, st t+4
      TILE_RF(O, E, 98304, 32768, tp5);   // tile t+2 (buf2): rd t+3, st t+5
      TILE_RF(E, O, 0,     65536, tp6);   // tile t+3 (buf3): rd t+4, st t+6
    }
  } else {
    for (int it = 0; it < 16; ++it) {
      const int t = it << 2;
      const size_t tp3 = (size_t)((t + 3) & 63) * 16384;
      const size_t tp4 = (size_t)((t + 4) & 63) * 16384;
      const size_t tp5 = (size_t)((t + 5) & 63) * 16384;
      const size_t tp6 = (size_t)((t + 6) & 63) * 16384;
      TILE_FR(O, E, 32768, 98304, tp3);
      TILE_FR(E, O, 65536, 0,     tp4);
      TILE_FR(O, E, 98304, 32768, tp5);
      TILE_FR(E, O, 0,     65536, tp6);
    }
  }
#undef STAGE
#undef STAGE_TILE
#undef RD8
#undef RDTILE
#undef MFMA
#undef MFMAC
#undef TAIL
#undef TILE_RF
#undef TILE_FR
#undef SBAR
#undef P1
#undef P0

  // Epilogue: +bias, round through fp16 (matches reference), store f32.
  // 32x32 C/D layout (verified r3-r11): col = lane&31,
  // row = (r&3) + 8*(r>>2) + 4*(lane>>5).
  #pragma unroll
  for (int n = 0; n < 2; ++n) {
    const int col = bni * 256 + wc * 64 + n * 32 + (lane & 31);
    const float bv = bias[col];
    #pragma unroll
    for (int m = 0; m < 4; ++m) {
      const int rbase = bmi * 256 + wr * 128 + m * 32 + ((lane >> 5) << 2);
      #pragma unroll
      for (int r = 0; r < 16; ++r) {
        const int row = rbase + (r & 3) + 8 * (r >> 2);
        C[(size_t)row * N_DIM + col] =
            __half2float(__float2half_rn(acc[m][n][r] + bv));
      }
    }
  }
}

// ---------------------------------------------------------------------------
extern "C" void kernel_launch(void* const* d_in, const int* in_sizes, int n_in,
                              void* d_out, int out_size, void* d_ws, size_t ws_size,
                              hipStream_t stream) {
  const float* x  = (const float*)d_in[0];   // [B,S,DIN] fp16-exact values in f32
  const float* w  = (const float*)d_in[1];   // [DOUT,DIN]
  const float* bs = (const float*)d_in[2];   // [DOUT]
  float* out = (float*)d_out;

  // Workspace: xq = 64 MiB e5m2 (tiled), wq = 16 MiB e4m3 (tiled)
  unsigned char* xq = (unsigned char*)d_ws;
  unsigned char* wq = (unsigned char*)d_ws + (size_t)M_DIM * K_DIM;

  // One fused quant launch: 16384 x-blocks + 4096 w-blocks.
  quant_fused_kernel<<<20480, 256, 0, stream>>>(x, w, (uint4*)xq, (uint4*)wq);

  gemm_fp8_kernel<<<1024, 512, 0, stream>>>(xq, wq, bs, out);
}